// Round 5
// baseline (960.718 us; speedup 1.0000x reference)
//
#include <hip/hip_runtime.h>
#include <hip/hip_bf16.h>
#include <math.h>

#define H 128
#define NG 1024

// K0: segment boundaries from sorted batch. seg[b] = first i with batch[i] >= b.
__global__ void k0_bounds(const int* __restrict__ batch, int N, int* __restrict__ seg) {
    int i = blockIdx.x * blockDim.x + threadIdx.x;
    if (i >= N) return;
    int cur = batch[i];
    int prev = (i == 0) ? -1 : batch[i - 1];
    for (int b = prev + 1; b <= cur; ++b) seg[b] = i;
    if (i == N - 1) {
        for (int b = cur + 1; b <= NG; ++b) seg[b] = N;
    }
}

// K1: sequential row-order f32 segment sum (np.add.at semantics).
// One block per graph, 128 threads = features. Thread k accumulates
// x[start..end-1, k] strictly in row order in f32; 8x preload unroll only
// pipelines the loads, never reorders the adds.
__global__ __launch_bounds__(128) void k1_seqsum(const float* __restrict__ x,
                                                 const int* __restrict__ seg,
                                                 float* __restrict__ sumx) {
    const int b = blockIdx.x;
    const int k = threadIdx.x;
    const int start = seg[b], end = seg[b + 1];

    const float* p = x + (size_t)start * H + k;
    float acc = 0.0f;
    int r = start;
    for (; r + 8 <= end; r += 8) {
        const float v0 = p[0 * H];
        const float v1 = p[1 * H];
        const float v2 = p[2 * H];
        const float v3 = p[3 * H];
        const float v4 = p[4 * H];
        const float v5 = p[5 * H];
        const float v6 = p[6 * H];
        const float v7 = p[7 * H];
        p += 8 * H;
        acc += v0; acc += v1; acc += v2; acc += v3;
        acc += v4; acc += v5; acc += v6; acc += v7;
    }
    for (; r < end; ++r) {
        acc += *p;
        p += H;
    }
    sumx[(size_t)b * H + k] = acc;
}

__device__ __forceinline__ double sigd(double v) { return 1.0 / (1.0 + exp(-v)); }

// K2: one block per graph, 512 threads = gate rows. Mimics the numpy reference's
// f32 data path: pooled_q[k] = f32 sequential sum of q[k] repeated cnt times
// (NOT cnt*q); h, c, gates stored rounded to f32 each iteration. Dot products
// and transcendentals in f64 (reference's BLAS/libm noise is the residual).
__global__ __launch_bounds__(512) void k2_lstm_pg(const float* __restrict__ sumx,
                                                  const int* __restrict__ seg,
                                                  const float* __restrict__ W_ih,
                                                  const float* __restrict__ W_hh,
                                                  const float* __restrict__ b_ih,
                                                  const float* __restrict__ b_hh,
                                                  float* __restrict__ out) {
    __shared__ float s_sx[H];
    __shared__ float s_pq[H];   // pooled q-part (f32 repeated-add chain)
    __shared__ float s_h[H];
    __shared__ float s_c[H];
    __shared__ float s_g[4 * H];

    const int b = blockIdx.x;
    const int r = threadIdx.x;  // gate row 0..511
    const int cnt = seg[b + 1] - seg[b];

    if (r < H) {
        s_sx[r] = sumx[(size_t)b * H + r];
        s_pq[r] = 0.0f;   // iteration 1: q_star = 0 -> chain of +0.0 = 0.0
        s_h[r] = 0.0f;
        s_c[r] = 0.0f;
    }
    __syncthreads();

    const double bias = (double)b_ih[r] + (double)b_hh[r];
    const float* w1 = W_ih + (size_t)r * (2 * H);       // cols 0..127 (x part)
    const float* wq = W_ih + (size_t)r * (2 * H) + H;   // cols 128..255 (q part)
    const float* wh = W_hh + (size_t)r * H;

    for (int it = 0; it < 3; ++it) {
        double acc = bias;
        for (int k = 0; k < H; ++k) acc += (double)w1[k] * (double)s_sx[k];
        for (int k = 0; k < H; ++k) acc += (double)wq[k] * (double)s_pq[k];
        for (int k = 0; k < H; ++k) acc += (double)wh[k] * (double)s_h[k];
        s_g[r] = (float)acc;   // gates are f32 arrays in the reference
        __syncthreads();

        if (r < H) {
            const double ig = (double)s_g[r];
            const double fg = (double)s_g[H + r];
            const double gg = (double)s_g[2 * H + r];
            const double og = (double)s_g[3 * H + r];
            const float c32 = (float)(sigd(fg) * (double)s_c[r] + sigd(ig) * tanh(gg));
            const float h32 = (float)(sigd(og) * tanh((double)c32));
            s_c[r] = c32;
            s_h[r] = h32;
        }
        __syncthreads();

        if (it < 2) {
            if (r < H) {
                // pooled_q[k] = f32 sum of h[k] added cnt times, sequentially
                // (what segment_sum does to the gathered q_exp rows).
                const float qv = s_h[r];
                float s = 0.0f;
                for (int j = 0; j < cnt; ++j) s += qv;  // no fast-math: stays a chain
                s_pq[r] = s;
            }
            __syncthreads();
        }
    }

    if (r < H) {
        const float hv = s_h[r];
        out[(size_t)b * (2 * H) + r] = hv;
        out[(size_t)b * (2 * H) + H + r] = hv;
    }
}

extern "C" void kernel_launch(void* const* d_in, const int* in_sizes, int n_in,
                              void* d_out, int out_size, void* d_ws, size_t ws_size,
                              hipStream_t stream) {
    const float* x     = (const float*)d_in[0];
    const int*   batch = (const int*)d_in[1];
    const float* W_ih  = (const float*)d_in[2];
    const float* W_hh  = (const float*)d_in[3];
    const float* b_ih  = (const float*)d_in[4];
    const float* b_hh  = (const float*)d_in[5];
    // Defensive: W_ih is (4H,2H)=131072 elems, W_hh is (4H,H)=65536. If the
    // delivered order differs, swap. (b_ih/b_hh order is insensitive: only summed.)
    if (in_sizes[2] == 4 * H * H && in_sizes[3] == 8 * H * H) {
        const float* t = W_ih; W_ih = W_hh; W_hh = t;
    }
    float* out = (float*)d_out;

    const int N = in_sizes[1];  // number of nodes

    int*   seg  = (int*)d_ws;                      // 1025 ints
    float* sumx = (float*)((char*)d_ws + 8192);    // 1024*128 f32 = 512 KB

    k0_bounds<<<(N + 255) / 256, 256, 0, stream>>>(batch, N, seg);
    k1_seqsum<<<NG, 128, 0, stream>>>(x, seg, sumx);
    k2_lstm_pg<<<NG, 512, 0, stream>>>(sumx, seg, W_ih, W_hh, b_ih, b_hh, out);
}

// Round 6
// 774.758 us; speedup vs baseline: 1.2400x; 1.2400x over previous
//
#include <hip/hip_runtime.h>
#include <hip/hip_bf16.h>
#include <math.h>

#define H 128
#define NG 1024
#define GPB 4

// K0: segment boundaries from sorted batch. seg[b] = first i with batch[i] >= b.
__global__ void k0_bounds(const int* __restrict__ batch, int N, int* __restrict__ seg) {
    int i = blockIdx.x * blockDim.x + threadIdx.x;
    if (i >= N) return;
    int cur = batch[i];
    int prev = (i == 0) ? -1 : batch[i - 1];
    for (int b = prev + 1; b <= cur; ++b) seg[b] = i;
    if (i == N - 1) {
        for (int b = cur + 1; b <= NG; ++b) seg[b] = N;
    }
}

// KT: transpose weights into [k][row] layout so k2's per-k loads are coalesced.
// WT1[k][r] = W_ih[r][k], WTq[k][r] = W_ih[r][128+k], WTh[k][r] = W_hh[r][k].
__global__ __launch_bounds__(256) void kT_transpose(const float* __restrict__ W_ih,
                                                    const float* __restrict__ W_hh,
                                                    float* __restrict__ WT1,
                                                    float* __restrict__ WTq,
                                                    float* __restrict__ WTh) {
    const int idx = blockIdx.x * 256 + threadIdx.x;  // 0..65535 = k*512 + r
    const int k = idx >> 9;
    const int r = idx & 511;
    WT1[idx] = W_ih[(size_t)r * 256 + k];
    WTq[idx] = W_ih[(size_t)r * 256 + 128 + k];
    WTh[idx] = W_hh[(size_t)r * 128 + k];
}

// K1: sequential row-order f32 segment sum (np.add.at semantics), 16-row preload.
// One block per graph, 128 threads = features; add order is strictly row order.
__global__ __launch_bounds__(128) void k1_seqsum(const float* __restrict__ x,
                                                 const int* __restrict__ seg,
                                                 float* __restrict__ sumx) {
    const int b = blockIdx.x;
    const int k = threadIdx.x;
    const int start = seg[b], end = seg[b + 1];

    const float* p = x + (size_t)start * H + k;
    float acc = 0.0f;
    int r = start;
    for (; r + 16 <= end; r += 16) {
        float v[16];
#pragma unroll
        for (int j = 0; j < 16; ++j) v[j] = p[j * H];
        p += 16 * H;
#pragma unroll
        for (int j = 0; j < 16; ++j) acc += v[j];
    }
    for (; r < end; ++r) {
        acc += *p;
        p += H;
    }
    sumx[(size_t)b * H + k] = acc;
}

__device__ __forceinline__ double sigd(double v) { return 1.0 / (1.0 + exp(-v)); }

// K2: GPB graphs per block, 512 threads = gate rows. Numerically identical op
// sequence to the r5 passing kernel: f64 acc = bias, then w1.sx (k asc), wq.pq,
// wh.h; gates/h/c rounded to f32; pooled_q = cnt-length sequential f32 add chain.
// Weights read from transposed layout: WT[k*512+r] -> coalesced 256B/wave.
__global__ __launch_bounds__(512) void k2_lstm(const float* __restrict__ sumx,
                                               const int* __restrict__ seg,
                                               const float* __restrict__ WT1,
                                               const float* __restrict__ WTq,
                                               const float* __restrict__ WTh,
                                               const float* __restrict__ b_ih,
                                               const float* __restrict__ b_hh,
                                               float* __restrict__ out) {
    __shared__ double s_sx[GPB][H];    // sum_x as f64 (cvt hoisted)
    __shared__ double s_pq[GPB][H];    // pooled q-part (f32 chain value, stored f64)
    __shared__ double s_h64[GPB][H];   // h (f32-rounded value, stored f64)
    __shared__ float  s_h[GPB][H];
    __shared__ float  s_c[GPB][H];
    __shared__ float  s_g[GPB][4 * H];
    __shared__ int    s_cnt[GPB];

    const int r = threadIdx.x;          // gate row 0..511
    const int g0 = blockIdx.x * GPB;

    if (r < GPB) s_cnt[r] = seg[g0 + r + 1] - seg[g0 + r];
    {
        const int g = r >> 7, f = r & 127;
        const float v = sumx[(size_t)(g0 + g) * H + f];
        s_sx[g][f] = (double)v;
        s_pq[g][f] = 0.0;
        s_h64[g][f] = 0.0;
        s_h[g][f] = 0.0f;
        s_c[g][f] = 0.0f;
    }
    __syncthreads();

    const double bias = (double)b_ih[r] + (double)b_hh[r];

    for (int it = 0; it < 3; ++it) {
        double acc[GPB];
#pragma unroll
        for (int g = 0; g < GPB; ++g) acc[g] = bias;

        for (int k = 0; k < H; ++k) {
            const double w = (double)WT1[k * 512 + r];
#pragma unroll
            for (int g = 0; g < GPB; ++g) acc[g] += w * s_sx[g][k];
        }
        if (it > 0) {  // it==0: pq = h = 0 -> terms are exact +0.0 (skippable)
            for (int k = 0; k < H; ++k) {
                const double w = (double)WTq[k * 512 + r];
#pragma unroll
                for (int g = 0; g < GPB; ++g) acc[g] += w * s_pq[g][k];
            }
            for (int k = 0; k < H; ++k) {
                const double w = (double)WTh[k * 512 + r];
#pragma unroll
                for (int g = 0; g < GPB; ++g) acc[g] += w * s_h64[g][k];
            }
        }
#pragma unroll
        for (int g = 0; g < GPB; ++g) s_g[g][r] = (float)acc[g];
        __syncthreads();

        {
            const int g = r >> 7, f = r & 127;
            const double ig = (double)s_g[g][f];
            const double fg = (double)s_g[g][H + f];
            const double gg = (double)s_g[g][2 * H + f];
            const double og = (double)s_g[g][3 * H + f];
            const float c32 = (float)(sigd(fg) * (double)s_c[g][f] + sigd(ig) * tanh(gg));
            const float h32 = (float)(sigd(og) * tanh((double)c32));
            s_c[g][f] = c32;
            s_h[g][f] = h32;
            s_h64[g][f] = (double)h32;
            if (it < 2) {
                // pooled_q[f] = f32 sum of h[f] added cnt times, sequentially.
                const float qv = h32;
                const int cnt = s_cnt[g];
                float s = 0.0f;
                for (int j = 0; j < cnt; ++j) s += qv;
                s_pq[g][f] = (double)s;
            }
        }
        __syncthreads();
    }

    {
        const int g = r >> 7, f = r & 127;
        const float hv = s_h[g][f];
        out[(size_t)(g0 + g) * (2 * H) + f] = hv;
        out[(size_t)(g0 + g) * (2 * H) + H + f] = hv;
    }
}

extern "C" void kernel_launch(void* const* d_in, const int* in_sizes, int n_in,
                              void* d_out, int out_size, void* d_ws, size_t ws_size,
                              hipStream_t stream) {
    const float* x     = (const float*)d_in[0];
    const int*   batch = (const int*)d_in[1];
    const float* W_ih  = (const float*)d_in[2];
    const float* W_hh  = (const float*)d_in[3];
    const float* b_ih  = (const float*)d_in[4];
    const float* b_hh  = (const float*)d_in[5];
    if (in_sizes[2] == 4 * H * H && in_sizes[3] == 8 * H * H) {
        const float* t = W_ih; W_ih = W_hh; W_hh = t;
    }
    float* out = (float*)d_out;

    const int N = in_sizes[1];

    // d_ws layout (poisoned 0xAA every call; everything rewritten below):
    int*   seg  = (int*)d_ws;                          //      0 .. 4100
    float* sumx = (float*)((char*)d_ws + 8192);        //   8192 .. 532480
    float* WT1  = (float*)((char*)d_ws + 540672);      // 128x512 f32 = 256 KB
    float* WTq  = (float*)((char*)d_ws + 802816);
    float* WTh  = (float*)((char*)d_ws + 1064960);

    kT_transpose<<<256, 256, 0, stream>>>(W_ih, W_hh, WT1, WTq, WTh);
    k0_bounds<<<(N + 255) / 256, 256, 0, stream>>>(batch, N, seg);
    k1_seqsum<<<NG, 128, 0, stream>>>(x, seg, sumx);
    k2_lstm<<<NG / GPB, 512, 0, stream>>>(sumx, seg, WT1, WTq, WTh, b_ih, b_hh, out);
}